// Round 9
// baseline (269.929 us; speedup 1.0000x reference)
//
#include <hip/hip_runtime.h>
#include <math.h>
#include <stdint.h>

#define B_   4
#define N_   2048
#define DIM_ 512
#define T_   16
#define H_   8
#define DH_  64
// num_patches = 128; 64-token tiles align within patches -> decay scalar per tile pair

typedef unsigned short ushort_t;
typedef unsigned int u32;
typedef __attribute__((ext_vector_type(8))) short bf16x8;    // 8 bf16 = 4 VGPRs
typedef __attribute__((ext_vector_type(16))) float f32x16;   // 32x32 MFMA acc

__device__ inline ushort_t bf16_rn(float x) {
  unsigned u = __builtin_bit_cast(unsigned, x);
  u += 0x7FFFu + ((u >> 16) & 1u);
  return (ushort_t)(u >> 16);
}
__device__ inline float bf16f(ushort_t h) {
  return __builtin_bit_cast(float, (unsigned)h << 16);
}
__device__ inline unsigned pack2(ushort_t a, ushort_t b) {
  return (unsigned)a | ((unsigned)b << 16);
}
__device__ inline void split2(float x, ushort_t &h, ushort_t &l) {
  h = bf16_rn(x);
  l = bf16_rn(x - bf16f(h));
}

// async global->LDS DMA, 16 B per lane; LDS dest = base + lane*16 (m104/m108)
__device__ __forceinline__ void gld16(const ushort_t* g, ushort_t* s) {
  __builtin_amdgcn_global_load_lds(
      (const __attribute__((address_space(1))) u32*)(uintptr_t)g,
      (__attribute__((address_space(3))) u32*)(uintptr_t)s, 16, 0, 0);
}

// ---------------------------------------------------------------------------
// Kernel A: transpose + hi/lo split of a weight matrix.
// src [K][Nn] fp32 row-major  ->  dh/dl [Nn][K] bf16 hi/lo.
// ---------------------------------------------------------------------------
__global__ __launch_bounds__(256) void transpose_split_kernel(
    const float* __restrict__ src, ushort_t* __restrict__ dh,
    ushort_t* __restrict__ dl, int K, int Nn) {
  __shared__ float Ts[64][68];
  int tid = threadIdx.x;
  int n0 = blockIdx.x * 64;
  int k0 = blockIdx.y * 64;
#pragma unroll
  for (int it = 0; it < 4; ++it) {
    int idx = tid + it * 256;
    int r = idx >> 4, c4 = (idx & 15) * 4;
    *(float4*)&Ts[r][c4] = *(const float4*)&src[(size_t)(k0 + r) * Nn + n0 + c4];
  }
  __syncthreads();
#pragma unroll
  for (int it = 0; it < 2; ++it) {
    int idx = tid + it * 256;
    int n = idx >> 3, kc = (idx & 7) * 8;
    ushort_t hs[8], ls[8];
#pragma unroll
    for (int j = 0; j < 8; ++j) split2(Ts[kc + j][n], hs[j], ls[j]);
    uint4 uh, ul;
    uh.x = pack2(hs[0], hs[1]); uh.y = pack2(hs[2], hs[3]);
    uh.z = pack2(hs[4], hs[5]); uh.w = pack2(hs[6], hs[7]);
    ul.x = pack2(ls[0], ls[1]); ul.y = pack2(ls[2], ls[3]);
    ul.z = pack2(ls[4], ls[5]); ul.w = pack2(ls[6], ls[7]);
    size_t o = (size_t)(n0 + n) * K + k0 + kc;
    *(uint4*)&dh[o] = uh;
    *(uint4*)&dl[o] = ul;
  }
}

// ---------------------------------------------------------------------------
// Kernel B: LayerNorm -> xn hi/lo bf16 [8192][512]. One wave per row.
// ---------------------------------------------------------------------------
__global__ __launch_bounds__(256) void ln_xn_kernel(
    const float* __restrict__ x, const float* __restrict__ gamma,
    const float* __restrict__ beta, ushort_t* __restrict__ xnh,
    ushort_t* __restrict__ xnl) {
  int row  = blockIdx.x * 4 + (threadIdx.x >> 6);
  int lane = threadIdx.x & 63;
  const float4* xr = (const float4*)(x + (size_t)row * DIM_);
  float4 v0 = xr[lane * 2 + 0];
  float4 v1 = xr[lane * 2 + 1];
  float s  = v0.x + v0.y + v0.z + v0.w + v1.x + v1.y + v1.z + v1.w;
  float ss = v0.x*v0.x + v0.y*v0.y + v0.z*v0.z + v0.w*v0.w
           + v1.x*v1.x + v1.y*v1.y + v1.z*v1.z + v1.w*v1.w;
#pragma unroll
  for (int off = 32; off > 0; off >>= 1) {
    s  += __shfl_xor(s, off);
    ss += __shfl_xor(ss, off);
  }
  float mu  = s * (1.0f / DIM_);
  float var = ss * (1.0f / DIM_) - mu * mu;
  float rstd = rsqrtf(var + 1e-5f);
  float4 g0 = *(const float4*)&gamma[lane * 8];
  float4 g1 = *(const float4*)&gamma[lane * 8 + 4];
  float4 b0 = *(const float4*)&beta[lane * 8];
  float4 b1 = *(const float4*)&beta[lane * 8 + 4];
  float xv[8] = {v0.x, v0.y, v0.z, v0.w, v1.x, v1.y, v1.z, v1.w};
  float gv[8] = {g0.x, g0.y, g0.z, g0.w, g1.x, g1.y, g1.z, g1.w};
  float bv[8] = {b0.x, b0.y, b0.z, b0.w, b1.x, b1.y, b1.z, b1.w};
  ushort_t hs[8], ls[8];
#pragma unroll
  for (int j = 0; j < 8; ++j) {
    float xn = (xv[j] - mu) * rstd * gv[j] + bv[j];
    split2(xn, hs[j], ls[j]);
  }
  uint4 uh, ul;
  uh.x = pack2(hs[0], hs[1]); uh.y = pack2(hs[2], hs[3]);
  uh.z = pack2(hs[4], hs[5]); uh.w = pack2(hs[6], hs[7]);
  ul.x = pack2(ls[0], ls[1]); ul.y = pack2(ls[2], ls[3]);
  ul.z = pack2(ls[4], ls[5]); ul.w = pack2(ls[6], ls[7]);
  size_t o = (size_t)row * DIM_ + lane * 8;
  *(uint4*)&xnh[o] = uh;
  *(uint4*)&xnl[o] = ul;
}

// ---------------------------------------------------------------------------
// Kernel C: qkv = xn @ Wqkv^T, split-bf16 3-product MFMA (32x32x16).
// 128x128 tile, K-step 32. Staging via global_load_lds DMA, double-buffered:
// 1 barrier/kt, load latency hidden behind MFMA. Rows = 32 shorts (64 B,
// 4x16B chunks), XOR swizzle phys = logical ^ (row&3) keeps b128 frag reads
// at the 8-cycle bank minimum (g=0/1 halves cover complementary chunks).
// NO long-lived prefetch regs (R5-R8 lesson).
// ---------------------------------------------------------------------------
__global__ __launch_bounds__(256) void qkv_gemm_mfma(
    const ushort_t* __restrict__ xnh, const ushort_t* __restrict__ xnl,
    const ushort_t* __restrict__ wth, const ushort_t* __restrict__ wtl,
    ushort_t* __restrict__ qh, ushort_t* __restrict__ ql,
    ushort_t* __restrict__ kho, ushort_t* __restrict__ klo,
    ushort_t* __restrict__ vt) {
  __shared__ ushort_t AhS[2][128 * 32], AlS[2][128 * 32];
  __shared__ ushort_t BhS[2][128 * 32], BlS[2][128 * 32];
  int tid = threadIdx.x;
  int w = tid >> 6, lane = tid & 63, l31 = lane & 31, g = lane >> 5;
  int wm = w >> 1, wn = w & 1;
  int n0 = blockIdx.x * 128;
  int m0 = blockIdx.y * 128;
  int rl4 = lane >> 2, p4 = lane & 3;

  f32x16 acc[2][2];
#pragma unroll
  for (int i = 0; i < 2; ++i)
#pragma unroll
    for (int j = 0; j < 2; ++j)
#pragma unroll
      for (int e = 0; e < 16; ++e) acc[i][j][e] = 0.0f;

  // loop-invariant swizzled fragment offsets (shorts)
  int offA[2][2], offB[2][2];
#pragma unroll
  for (int rb = 0; rb < 2; ++rb)
#pragma unroll
    for (int kc = 0; kc < 2; ++kc) {
      int rA = wm * 64 + rb * 32 + l31;
      int rB = wn * 64 + rb * 32 + l31;
      offA[rb][kc] = rA * 32 + (((kc * 2 + g) ^ (rA & 3)) * 8);
      offB[rb][kc] = rB * 32 + (((kc * 2 + g) ^ (rB & 3)) * 8);
    }

  // prologue: DMA tile 0 -> set 0
#pragma unroll
  for (int i = 0; i < 2; ++i) {
    int rbase = w * 32 + i * 16;
    int row = rbase + rl4;
    int c = p4 ^ (row & 3);
    gld16(&xnh[(size_t)(m0 + row) * 512 + c * 8], &AhS[0][rbase * 32]);
    gld16(&xnl[(size_t)(m0 + row) * 512 + c * 8], &AlS[0][rbase * 32]);
    gld16(&wth[(size_t)(n0 + row) * 512 + c * 8], &BhS[0][rbase * 32]);
    gld16(&wtl[(size_t)(n0 + row) * 512 + c * 8], &BlS[0][rbase * 32]);
  }

#pragma unroll 1
  for (int kt = 0; kt < 16; ++kt) {
    int cur = kt & 1, nxt = cur ^ 1;
    __syncthreads();                       // drains DMA -> cur ready; prev readers done with nxt
    int ktn = (kt + 1) & 15;               // wrap: constant work, last DMA harmless
#pragma unroll
    for (int i = 0; i < 2; ++i) {
      int rbase = w * 32 + i * 16;
      int row = rbase + rl4;
      int c = p4 ^ (row & 3);
      gld16(&xnh[(size_t)(m0 + row) * 512 + ktn * 32 + c * 8], &AhS[nxt][rbase * 32]);
      gld16(&xnl[(size_t)(m0 + row) * 512 + ktn * 32 + c * 8], &AlS[nxt][rbase * 32]);
      gld16(&wth[(size_t)(n0 + row) * 512 + ktn * 32 + c * 8], &BhS[nxt][rbase * 32]);
      gld16(&wtl[(size_t)(n0 + row) * 512 + ktn * 32 + c * 8], &BlS[nxt][rbase * 32]);
    }
#pragma unroll
    for (int kc = 0; kc < 2; ++kc) {
      bf16x8 afh[2], afl[2], bfh[2], bfl[2];
#pragma unroll
      for (int rb = 0; rb < 2; ++rb) {
        afh[rb] = *(const bf16x8*)&AhS[cur][offA[rb][kc]];
        afl[rb] = *(const bf16x8*)&AlS[cur][offA[rb][kc]];
      }
#pragma unroll
      for (int cb = 0; cb < 2; ++cb) {
        bfh[cb] = *(const bf16x8*)&BhS[cur][offB[cb][kc]];
        bfl[cb] = *(const bf16x8*)&BlS[cur][offB[cb][kc]];
      }
#pragma unroll
      for (int rb = 0; rb < 2; ++rb)
#pragma unroll
        for (int cb = 0; cb < 2; ++cb) {
          acc[rb][cb] = __builtin_amdgcn_mfma_f32_32x32x16_bf16(afh[rb], bfh[cb], acc[rb][cb], 0, 0, 0);
          acc[rb][cb] = __builtin_amdgcn_mfma_f32_32x32x16_bf16(afh[rb], bfl[cb], acc[rb][cb], 0, 0, 0);
          acc[rb][cb] = __builtin_amdgcn_mfma_f32_32x32x16_bf16(afl[rb], bfh[cb], acc[rb][cb], 0, 0, 0);
        }
    }
  }

  // epilogue: part uniform per block (n0: 0-383 q, 512.. k, 1024.. v)
  int part = n0 >> 9;
#pragma unroll
  for (int rb = 0; rb < 2; ++rb) {
    int m_base = m0 + wm * 64 + rb * 32;
#pragma unroll
    for (int cb = 0; cb < 2; ++cb) {
      int n_g = n0 + wn * 64 + cb * 32 + l31;
      int rem = n_g & 511, hh = rem >> 6, d = rem & 63;
      if (part == 2) {
#pragma unroll
        for (int grp = 0; grp < 4; ++grp) {
          int m_g = m_base + grp * 8 + 4 * g;
          int bb = m_g >> 11, tok = m_g & 2047;
          uint2 pk;
          pk.x = pack2(bf16_rn(acc[rb][cb][grp * 4 + 0]), bf16_rn(acc[rb][cb][grp * 4 + 1]));
          pk.y = pack2(bf16_rn(acc[rb][cb][grp * 4 + 2]), bf16_rn(acc[rb][cb][grp * 4 + 3]));
          *(uint2*)&vt[((size_t)(bb * 8 + hh) * 64 + d) * 2048 + tok] = pk;
        }
      } else {
        float sc = (part == 0) ? 0.125f : 1.0f;
        ushort_t* dsth = (part == 0) ? qh : kho;
        ushort_t* dstl = (part == 0) ? ql : klo;
#pragma unroll
        for (int reg = 0; reg < 16; ++reg) {
          int row = (reg & 3) + 8 * (reg >> 2) + 4 * g;
          int m_g = m_base + row;
          int bb = m_g >> 11, tok = m_g & 2047;
          ushort_t hi, lo;
          split2(acc[rb][cb][reg] * sc, hi, lo);
          size_t addr = ((size_t)(bb * 8 + hh) * 2048 + tok) * 64 + d;
          dsth[addr] = hi;
          dstl[addr] = lo;
        }
      }
    }
  }
}

// ---------------------------------------------------------------------------
// Kernel D: MFMA attention, DMA-staged + double-buffered K/Kl/Vt.
// grid x = bh (XCD affinity), y = qt. 2 barriers/kt (was 3); DMA of kt+1
// issued at loop top, drained by the mid (P) barrier -> latency hidden
// behind the S-MFMA + exp phase. Rows = 64 shorts, XOR-8 chunk swizzle.
// PS stays stride-72 (measured conflict-free).
// ---------------------------------------------------------------------------
__global__ __launch_bounds__(256) void attn_mfma(
    const ushort_t* __restrict__ qh, const ushort_t* __restrict__ ql,
    const ushort_t* __restrict__ kho, const ushort_t* __restrict__ klo,
    const ushort_t* __restrict__ vt, const float* __restrict__ R,
    const float* __restrict__ a, const float* __restrict__ c,
    ushort_t* __restrict__ aoh, ushort_t* __restrict__ aol) {
  __shared__ ushort_t KhS[2][64 * 64], KlS[2][64 * 64], VtS[2][64 * 64];
  __shared__ ushort_t PS[64 * 72];
  __shared__ float rsLDS[2][64];

  int tid = threadIdx.x;
  int w = tid >> 6, lane = tid & 63, l31 = lane & 31, g = lane >> 5;
  int qhalf = w >> 1, khalf = w & 1;
  int bh = blockIdx.x;
  int qt = blockIdx.y;
  int b = bh >> 3, h = bh & 7;
  float aab = fabsf(a[h]);
  float cab = fabsf(c[h]);
  int rl8 = lane >> 3, p8 = lane & 7;

  // Q fragments straight from global (pre-scaled hi/lo)
  size_t qoff = ((size_t)bh * 2048 + qt * 64 + qhalf * 32 + l31) * 64;
  bf16x8 qfh[4], qfl[4];
#pragma unroll
  for (int d0i = 0; d0i < 4; ++d0i) {
    qfh[d0i] = *(const bf16x8*)&qh[qoff + d0i * 16 + 8 * g];
    qfl[d0i] = *(const bf16x8*)&ql[qoff + d0i * 16 + 8 * g];
  }

  const ushort_t* kbase = kho + (size_t)bh * 2048 * 64;
  const ushort_t* lbase = klo + (size_t)bh * 2048 * 64;
  const ushort_t* vbase = vt + (size_t)bh * 64 * 2048;

  // loop-invariant swizzled frag offsets (shorts); same geometry for K and Vt
  int koff[4];
  {
    int r = khalf * 32 + l31;
#pragma unroll
    for (int d0i = 0; d0i < 4; ++d0i)
      koff[d0i] = r * 64 + (((d0i * 2 + g) ^ (r & 7)) * 8);
  }

  // prologue: DMA tile 0 -> set 0
#pragma unroll
  for (int i = 0; i < 2; ++i) {
    int rbase = w * 16 + i * 8;
    int row = rbase + rl8;
    int cc = p8 ^ (row & 7);
    gld16(&kbase[(size_t)row * 64 + cc * 8], &KhS[0][rbase * 64]);
    gld16(&lbase[(size_t)row * 64 + cc * 8], &KlS[0][rbase * 64]);
    gld16(&vbase[(size_t)row * 2048 + cc * 8], &VtS[0][rbase * 64]);
  }

  f32x16 oacc;
#pragma unroll
  for (int i = 0; i < 16; ++i) oacc[i] = 0.0f;
  float rs_acc[16] = {};
  int ti = qt >> 1;

#pragma unroll 1
  for (int kt = 0; kt < 32; ++kt) {
    int cur = kt & 1, nxt = cur ^ 1;
    __syncthreads();                 // cur DMA drained; prev PV done reading nxt-target
    int ktn = (kt + 1) & 31;         // wrap: constant work, last DMA harmless
#pragma unroll
    for (int i = 0; i < 2; ++i) {
      int rbase = w * 16 + i * 8;
      int row = rbase + rl8;
      int cc = p8 ^ (row & 7);
      gld16(&kbase[(size_t)(ktn * 64 + row) * 64 + cc * 8], &KhS[nxt][rbase * 64]);
      gld16(&lbase[(size_t)(ktn * 64 + row) * 64 + cc * 8], &KlS[nxt][rbase * 64]);
      gld16(&vbase[(size_t)row * 2048 + ktn * 64 + cc * 8], &VtS[nxt][rbase * 64]);
    }

    // S = Q K^T (3-product split)
    f32x16 sacc;
#pragma unroll
    for (int i = 0; i < 16; ++i) sacc[i] = 0.0f;
#pragma unroll
    for (int d0i = 0; d0i < 4; ++d0i) {
      bf16x8 kfh = *(const bf16x8*)&KhS[cur][koff[d0i]];
      bf16x8 kfl = *(const bf16x8*)&KlS[cur][koff[d0i]];
      sacc = __builtin_amdgcn_mfma_f32_32x32x16_bf16(qfh[d0i], kfh, sacc, 0, 0, 0);
      sacc = __builtin_amdgcn_mfma_f32_32x32x16_bf16(qfh[d0i], kfl, sacc, 0, 0, 0);
      sacc = __builtin_amdgcn_mfma_f32_32x32x16_bf16(qfl[d0i], kfh, sacc, 0, 0, 0);
    }

    float Rv = R[b * (T_ * T_) + ti * T_ + (kt >> 1)];
    float dec = 1.0f / (1.0f + __expf(aab * Rv - cab));
#pragma unroll
    for (int reg = 0; reg < 16; ++reg) {
      float pv = __expf(fmaxf(sacc[reg], 0.0f) * dec);
      rs_acc[reg] += pv;
      int row = (reg & 3) + 8 * (reg >> 2) + 4 * g;
      PS[(qhalf * 32 + row) * 72 + khalf * 32 + l31] = bf16_rn(pv);
    }
    __syncthreads();                 // P visible; also drains nxt DMA

    // O += P V
#pragma unroll
    for (int k0i = 0; k0i < 4; ++k0i) {
      bf16x8 pf = *(const bf16x8*)&PS[(qhalf * 32 + l31) * 72 + k0i * 16 + 8 * g];
      bf16x8 vf = *(const bf16x8*)&VtS[cur][koff[k0i]];
      oacc = __builtin_amdgcn_mfma_f32_32x32x16_bf16(pf, vf, oacc, 0, 0, 0);
    }
  }

  // row-sum combine
#pragma unroll
  for (int reg = 0; reg < 16; ++reg) {
    float vsum = rs_acc[reg];
    vsum += __shfl_xor(vsum, 1);
    vsum += __shfl_xor(vsum, 2);
    vsum += __shfl_xor(vsum, 4);
    vsum += __shfl_xor(vsum, 8);
    vsum += __shfl_xor(vsum, 16);
    rs_acc[reg] = vsum;
  }
  if (l31 == 0) {
#pragma unroll
    for (int reg = 0; reg < 16; ++reg) {
      int row = (reg & 3) + 8 * (reg >> 2) + 4 * g;
      rsLDS[khalf][qhalf * 32 + row] = rs_acc[reg];
    }
  }
  __syncthreads();

  // normalize + write aout hi/lo [b][tok][h*64+d]
#pragma unroll
  for (int reg = 0; reg < 16; ++reg) {
    int row = (reg & 3) + 8 * (reg >> 2) + 4 * g;
    int qg = qhalf * 32 + row;
    float invs = 1.0f / (rsLDS[0][qg] + rsLDS[1][qg]);
    int tok = qt * 64 + qg;
    int d = khalf * 32 + l31;
    ushort_t hi, lo;
    split2(oacc[reg] * invs, hi, lo);
    size_t addr = ((size_t)b * 2048 + tok) * 512 + h * 64 + d;
    aoh[addr] = hi;
    aol[addr] = lo;
  }
}

// ---------------------------------------------------------------------------
// Kernel E: out = aout @ Wout^T. Same DMA-dbuf structure as C, fp32 output.
// ---------------------------------------------------------------------------
__global__ __launch_bounds__(256) void out_gemm_mfma(
    const ushort_t* __restrict__ ah, const ushort_t* __restrict__ al,
    const ushort_t* __restrict__ wth, const ushort_t* __restrict__ wtl,
    float* __restrict__ out) {
  __shared__ ushort_t AhS[2][128 * 32], AlS[2][128 * 32];
  __shared__ ushort_t BhS[2][128 * 32], BlS[2][128 * 32];
  int tid = threadIdx.x;
  int w = tid >> 6, lane = tid & 63, l31 = lane & 31, g = lane >> 5;
  int wm = w >> 1, wn = w & 1;
  int n0 = blockIdx.x * 128;
  int m0 = blockIdx.y * 128;
  int rl4 = lane >> 2, p4 = lane & 3;

  f32x16 acc[2][2];
#pragma unroll
  for (int i = 0; i < 2; ++i)
#pragma unroll
    for (int j = 0; j < 2; ++j)
#pragma unroll
      for (int e = 0; e < 16; ++e) acc[i][j][e] = 0.0f;

  int offA[2][2], offB[2][2];
#pragma unroll
  for (int rb = 0; rb < 2; ++rb)
#pragma unroll
    for (int kc = 0; kc < 2; ++kc) {
      int rA = wm * 64 + rb * 32 + l31;
      int rB = wn * 64 + rb * 32 + l31;
      offA[rb][kc] = rA * 32 + (((kc * 2 + g) ^ (rA & 3)) * 8);
      offB[rb][kc] = rB * 32 + (((kc * 2 + g) ^ (rB & 3)) * 8);
    }

#pragma unroll
  for (int i = 0; i < 2; ++i) {
    int rbase = w * 32 + i * 16;
    int row = rbase + rl4;
    int c = p4 ^ (row & 3);
    gld16(&ah[(size_t)(m0 + row) * 512 + c * 8], &AhS[0][rbase * 32]);
    gld16(&al[(size_t)(m0 + row) * 512 + c * 8], &AlS[0][rbase * 32]);
    gld16(&wth[(size_t)(n0 + row) * 512 + c * 8], &BhS[0][rbase * 32]);
    gld16(&wtl[(size_t)(n0 + row) * 512 + c * 8], &BlS[0][rbase * 32]);
  }

#pragma unroll 1
  for (int kt = 0; kt < 16; ++kt) {
    int cur = kt & 1, nxt = cur ^ 1;
    __syncthreads();
    int ktn = (kt + 1) & 15;
#pragma unroll
    for (int i = 0; i < 2; ++i) {
      int rbase = w * 32 + i * 16;
      int row = rbase + rl4;
      int c = p4 ^ (row & 3);
      gld16(&ah[(size_t)(m0 + row) * 512 + ktn * 32 + c * 8], &AhS[nxt][rbase * 32]);
      gld16(&al[(size_t)(m0 + row) * 512 + ktn * 32 + c * 8], &AlS[nxt][rbase * 32]);
      gld16(&wth[(size_t)(n0 + row) * 512 + ktn * 32 + c * 8], &BhS[nxt][rbase * 32]);
      gld16(&wtl[(size_t)(n0 + row) * 512 + ktn * 32 + c * 8], &BlS[nxt][rbase * 32]);
    }
#pragma unroll
    for (int kc = 0; kc < 2; ++kc) {
      bf16x8 afh[2], afl[2], bfh[2], bfl[2];
#pragma unroll
      for (int rb = 0; rb < 2; ++rb) {
        afh[rb] = *(const bf16x8*)&AhS[cur][offA[rb][kc]];
        afl[rb] = *(const bf16x8*)&AlS[cur][offA[rb][kc]];
      }
#pragma unroll
      for (int cb = 0; cb < 2; ++cb) {
        bfh[cb] = *(const bf16x8*)&BhS[cur][offB[cb][kc]];
        bfl[cb] = *(const bf16x8*)&BlS[cur][offB[cb][kc]];
      }
#pragma unroll
      for (int rb = 0; rb < 2; ++rb)
#pragma unroll
        for (int cb = 0; cb < 2; ++cb) {
          acc[rb][cb] = __builtin_amdgcn_mfma_f32_32x32x16_bf16(afh[rb], bfh[cb], acc[rb][cb], 0, 0, 0);
          acc[rb][cb] = __builtin_amdgcn_mfma_f32_32x32x16_bf16(afh[rb], bfl[cb], acc[rb][cb], 0, 0, 0);
          acc[rb][cb] = __builtin_amdgcn_mfma_f32_32x32x16_bf16(afl[rb], bfh[cb], acc[rb][cb], 0, 0, 0);
        }
    }
  }

#pragma unroll
  for (int rb = 0; rb < 2; ++rb) {
    int m_base = m0 + wm * 64 + rb * 32;
#pragma unroll
    for (int cb = 0; cb < 2; ++cb) {
      int n_g = n0 + wn * 64 + cb * 32 + l31;
#pragma unroll
      for (int reg = 0; reg < 16; ++reg) {
        int row = (reg & 3) + 8 * (reg >> 2) + 4 * g;
        out[(size_t)(m_base + row) * 512 + n_g] = acc[rb][cb][reg];
      }
    }
  }
}

// ---------------------------------------------------------------------------
extern "C" void kernel_launch(void* const* d_in, const int* in_sizes, int n_in,
                              void* d_out, int out_size, void* d_ws, size_t ws_size,
                              hipStream_t stream) {
  (void)in_sizes; (void)n_in;
  const float* x     = (const float*)d_in[0];
  const float* R     = (const float*)d_in[1];
  const float* gamma = (const float*)d_in[2];
  const float* beta  = (const float*)d_in[3];
  const float* Wqkv  = (const float*)d_in[4];
  const float* Wout  = (const float*)d_in[5];
  const float* av    = (const float*)d_in[6];
  const float* cv    = (const float*)d_in[7];
  float* out = (float*)d_out;

  const size_t EL  = (size_t)B_ * N_ * DIM_;     // 4,194,304 elements
  const size_t SZT = EL * sizeof(ushort_t);      // 8 MiB per bf16 tensor

  char* p = (char*)d_ws;
  ushort_t* wqh = (ushort_t*)p;                  p += (size_t)1536 * 512 * 2;
  ushort_t* wql = (ushort_t*)p;                  p += (size_t)1536 * 512 * 2;
  ushort_t* woh = (ushort_t*)p;                  p += (size_t)512 * 512 * 2;
  ushort_t* wol = (ushort_t*)p;                  p += (size_t)512 * 512 * 2;
  ushort_t* qhb = (ushort_t*)p;                  p += SZT;
  ushort_t* qlb = (ushort_t*)p;                  p += SZT;
  ushort_t* khb = (ushort_t*)p;                  p += SZT;
  ushort_t* klb = (ushort_t*)p;                  p += SZT;
  ushort_t* vtb = (ushort_t*)p;                  p += SZT;
  size_t base_need = (size_t)(p - (char*)d_ws);
  size_t needA = base_need + 2 * SZT;

  bool planA = (ws_size >= needA);
  // xn hi/lo doubles as aout hi/lo (xn dead after qkv_gemm).
  ushort_t* xnh = planA ? (ushort_t*)p : (ushort_t*)d_out;
  ushort_t* xnl = xnh + EL;
  float* gemm_dst = planA ? out : (float*)qhb;   // qh+ql region dead by then

  transpose_split_kernel<<<dim3(24, 8), dim3(256), 0, stream>>>(Wqkv, wqh, wql, 512, 1536);
  transpose_split_kernel<<<dim3(8, 8), dim3(256), 0, stream>>>(Wout, woh, wol, 512, 512);
  ln_xn_kernel<<<dim3(2048), dim3(256), 0, stream>>>(x, gamma, beta, xnh, xnl);
  qkv_gemm_mfma<<<dim3(12, 64), dim3(256), 0, stream>>>(xnh, xnl, wqh, wql,
                                                        qhb, qlb, khb, klb, vtb);
  attn_mfma<<<dim3(32, 32), dim3(256), 0, stream>>>(qhb, qlb, khb, klb, vtb,
                                                    R, av, cv, xnh, xnl);
  out_gemm_mfma<<<dim3(4, 64), dim3(256), 0, stream>>>(xnh, xnl, woh, wol, gemm_dst);
  if (!planA) {
    hipMemcpyAsync(out, gemm_dst, (size_t)out_size * sizeof(float),
                   hipMemcpyDeviceToDevice, stream);
  }
}

// Round 10
// 267.796 us; speedup vs baseline: 1.0080x; 1.0080x over previous
//
#include <hip/hip_runtime.h>
#include <math.h>

#define B_   4
#define N_   2048
#define DIM_ 512
#define T_   16
#define H_   8
#define DH_  64
// num_patches = 128; 64-token tiles align within patches -> decay scalar per tile pair

typedef unsigned short ushort_t;
typedef __attribute__((ext_vector_type(8))) short bf16x8;    // 8 bf16 = 4 VGPRs
typedef __attribute__((ext_vector_type(16))) float f32x16;   // 32x32 MFMA acc

__device__ inline ushort_t bf16_rn(float x) {
  unsigned u = __builtin_bit_cast(unsigned, x);
  u += 0x7FFFu + ((u >> 16) & 1u);
  return (ushort_t)(u >> 16);
}
__device__ inline float bf16f(ushort_t h) {
  return __builtin_bit_cast(float, (unsigned)h << 16);
}
__device__ inline unsigned pack2(ushort_t a, ushort_t b) {
  return (unsigned)a | ((unsigned)b << 16);
}
__device__ inline void split2(float x, ushort_t &h, ushort_t &l) {
  h = bf16_rn(x);
  l = bf16_rn(x - bf16f(h));
}

// ---------------------------------------------------------------------------
// Kernel A: merged prep. Blocks 0..191: Wqkv transpose+split; 192..255: Wout;
// 256..2303: LayerNorm -> xn hi/lo. One launch instead of three.
// ---------------------------------------------------------------------------
__global__ __launch_bounds__(256) void prep_kernel(
    const float* __restrict__ x, const float* __restrict__ gamma,
    const float* __restrict__ beta, const float* __restrict__ Wqkv,
    const float* __restrict__ Wout,
    ushort_t* __restrict__ xnh, ushort_t* __restrict__ xnl,
    ushort_t* __restrict__ wqh, ushort_t* __restrict__ wql,
    ushort_t* __restrict__ woh, ushort_t* __restrict__ wol) {
  __shared__ float Ts[64][68];
  int bidx = blockIdx.x;
  int tid = threadIdx.x;
  if (bidx < 256) {
    const float* src; ushort_t* dh; ushort_t* dl; int Nn, n0, k0;
    if (bidx < 192) {
      src = Wqkv; dh = wqh; dl = wql; Nn = 1536;
      n0 = (bidx % 24) * 64; k0 = (bidx / 24) * 64;
    } else {
      int l = bidx - 192;
      src = Wout; dh = woh; dl = wol; Nn = 512;
      n0 = (l % 8) * 64; k0 = (l / 8) * 64;
    }
#pragma unroll
    for (int it = 0; it < 4; ++it) {
      int idx = tid + it * 256;
      int r = idx >> 4, c4 = (idx & 15) * 4;
      *(float4*)&Ts[r][c4] = *(const float4*)&src[(size_t)(k0 + r) * Nn + n0 + c4];
    }
    __syncthreads();
#pragma unroll
    for (int it = 0; it < 2; ++it) {
      int idx = tid + it * 256;
      int n = idx >> 3, kc = (idx & 7) * 8;
      ushort_t hs[8], ls[8];
#pragma unroll
      for (int j = 0; j < 8; ++j) split2(Ts[kc + j][n], hs[j], ls[j]);
      uint4 uh, ul;
      uh.x = pack2(hs[0], hs[1]); uh.y = pack2(hs[2], hs[3]);
      uh.z = pack2(hs[4], hs[5]); uh.w = pack2(hs[6], hs[7]);
      ul.x = pack2(ls[0], ls[1]); ul.y = pack2(ls[2], ls[3]);
      ul.z = pack2(ls[4], ls[5]); ul.w = pack2(ls[6], ls[7]);
      size_t o = (size_t)(n0 + n) * 512 + k0 + kc;
      *(uint4*)&dh[o] = uh;
      *(uint4*)&dl[o] = ul;
    }
  } else {
    int row  = (bidx - 256) * 4 + (tid >> 6);
    int lane = tid & 63;
    const float4* xr = (const float4*)(x + (size_t)row * DIM_);
    float4 v0 = xr[lane * 2 + 0];
    float4 v1 = xr[lane * 2 + 1];
    float s  = v0.x + v0.y + v0.z + v0.w + v1.x + v1.y + v1.z + v1.w;
    float ss = v0.x*v0.x + v0.y*v0.y + v0.z*v0.z + v0.w*v0.w
             + v1.x*v1.x + v1.y*v1.y + v1.z*v1.z + v1.w*v1.w;
#pragma unroll
    for (int off = 32; off > 0; off >>= 1) {
      s  += __shfl_xor(s, off);
      ss += __shfl_xor(ss, off);
    }
    float mu  = s * (1.0f / DIM_);
    float var = ss * (1.0f / DIM_) - mu * mu;
    float rstd = rsqrtf(var + 1e-5f);
    float4 g0 = *(const float4*)&gamma[lane * 8];
    float4 g1 = *(const float4*)&gamma[lane * 8 + 4];
    float4 b0 = *(const float4*)&beta[lane * 8];
    float4 b1 = *(const float4*)&beta[lane * 8 + 4];
    float xv[8] = {v0.x, v0.y, v0.z, v0.w, v1.x, v1.y, v1.z, v1.w};
    float gv[8] = {g0.x, g0.y, g0.z, g0.w, g1.x, g1.y, g1.z, g1.w};
    float bv[8] = {b0.x, b0.y, b0.z, b0.w, b1.x, b1.y, b1.z, b1.w};
    ushort_t hs[8], ls[8];
#pragma unroll
    for (int j = 0; j < 8; ++j) {
      float xn = (xv[j] - mu) * rstd * gv[j] + bv[j];
      split2(xn, hs[j], ls[j]);
    }
    uint4 uh, ul;
    uh.x = pack2(hs[0], hs[1]); uh.y = pack2(hs[2], hs[3]);
    uh.z = pack2(hs[4], hs[5]); uh.w = pack2(hs[6], hs[7]);
    ul.x = pack2(ls[0], ls[1]); ul.y = pack2(ls[2], ls[3]);
    ul.z = pack2(ls[4], ls[5]); ul.w = pack2(ls[6], ls[7]);
    size_t o = (size_t)row * DIM_ + lane * 8;
    *(uint4*)&xnh[o] = uh;
    *(uint4*)&xnl[o] = ul;
  }
}

// ---------------------------------------------------------------------------
// Kernel C: qkv = xn @ Wqkv^T, split-bf16 3-product MFMA (32x32x16).
// R8-proven body (load->immediate ds_write, stride 40, no prefetch regs,
// no min-waves bound). 1D grid with XCD-aware decode: each XCD gets all
// 12 n-blocks x an 8-strided m-slice -> per-XCD fetch ~ 2 MB xn + 6 MB W.
// ---------------------------------------------------------------------------
__global__ __launch_bounds__(256) void qkv_gemm_mfma(
    const ushort_t* __restrict__ xnh, const ushort_t* __restrict__ xnl,
    const ushort_t* __restrict__ wth, const ushort_t* __restrict__ wtl,
    ushort_t* __restrict__ qh, ushort_t* __restrict__ ql,
    ushort_t* __restrict__ kho, ushort_t* __restrict__ klo,
    ushort_t* __restrict__ vt) {
  __shared__ ushort_t Ah[128 * 40], Al[128 * 40], Bh[128 * 40], Bl[128 * 40];
  int tid = threadIdx.x;
  int w = tid >> 6, lane = tid & 63, l31 = lane & 31, g = lane >> 5;
  int wm = w >> 1, wn = w & 1;
  // XCD-aware decode (blocks round-robin XCDs by index)
  int idx = blockIdx.x;
  int xcd = idx & 7, local = idx >> 3;
  int n0 = (local % 12) * 128;
  int m0 = ((local / 12) * 8 + xcd) * 128;

  f32x16 acc[2][2];
#pragma unroll
  for (int i = 0; i < 2; ++i)
#pragma unroll
    for (int j = 0; j < 2; ++j)
#pragma unroll
      for (int e = 0; e < 16; ++e) acc[i][j][e] = 0.0f;

  int fm[2], fc[2];
#pragma unroll
  for (int it = 0; it < 2; ++it) {
    int f = tid + it * 256;
    fm[it] = f >> 2;
    fc[it] = (f & 3) * 8;
  }

#pragma unroll 1
  for (int kt = 0; kt < 16; ++kt) {
    __syncthreads();
#pragma unroll
    for (int it = 0; it < 2; ++it) {
      size_t ao = (size_t)(m0 + fm[it]) * 512 + kt * 32 + fc[it];
      size_t bo = (size_t)(n0 + fm[it]) * 512 + kt * 32 + fc[it];
      uint4 tah = *(const uint4*)&xnh[ao];
      uint4 tal = *(const uint4*)&xnl[ao];
      uint4 tbh = *(const uint4*)&wth[bo];
      uint4 tbl = *(const uint4*)&wtl[bo];
      int o = fm[it] * 40 + fc[it];
      *(uint4*)&Ah[o] = tah;
      *(uint4*)&Al[o] = tal;
      *(uint4*)&Bh[o] = tbh;
      *(uint4*)&Bl[o] = tbl;
    }
    __syncthreads();
#pragma unroll
    for (int kc = 0; kc < 2; ++kc) {
      int off = kc * 16 + 8 * g;
      bf16x8 afh[2], afl[2], bfh[2], bfl[2];
#pragma unroll
      for (int rb = 0; rb < 2; ++rb) {
        int r = (wm * 64 + rb * 32 + l31) * 40 + off;
        afh[rb] = *(const bf16x8*)&Ah[r];
        afl[rb] = *(const bf16x8*)&Al[r];
      }
#pragma unroll
      for (int cb = 0; cb < 2; ++cb) {
        int r = (wn * 64 + cb * 32 + l31) * 40 + off;
        bfh[cb] = *(const bf16x8*)&Bh[r];
        bfl[cb] = *(const bf16x8*)&Bl[r];
      }
#pragma unroll
      for (int rb = 0; rb < 2; ++rb)
#pragma unroll
        for (int cb = 0; cb < 2; ++cb) {
          acc[rb][cb] = __builtin_amdgcn_mfma_f32_32x32x16_bf16(afh[rb], bfh[cb], acc[rb][cb], 0, 0, 0);
          acc[rb][cb] = __builtin_amdgcn_mfma_f32_32x32x16_bf16(afh[rb], bfl[cb], acc[rb][cb], 0, 0, 0);
          acc[rb][cb] = __builtin_amdgcn_mfma_f32_32x32x16_bf16(afl[rb], bfh[cb], acc[rb][cb], 0, 0, 0);
        }
    }
  }

  // epilogue: part uniform per block (n0: 0-383 q, 512.. k, 1024.. v)
  int part = n0 >> 9;
#pragma unroll
  for (int rb = 0; rb < 2; ++rb) {
    int m_base = m0 + wm * 64 + rb * 32;
#pragma unroll
    for (int cb = 0; cb < 2; ++cb) {
      int n_g = n0 + wn * 64 + cb * 32 + l31;
      int rem = n_g & 511, hh = rem >> 6, d = rem & 63;
      if (part == 2) {
#pragma unroll
        for (int grp = 0; grp < 4; ++grp) {
          int m_g = m_base + grp * 8 + 4 * g;
          int bb = m_g >> 11, tok = m_g & 2047;
          uint2 pk;
          pk.x = pack2(bf16_rn(acc[rb][cb][grp * 4 + 0]), bf16_rn(acc[rb][cb][grp * 4 + 1]));
          pk.y = pack2(bf16_rn(acc[rb][cb][grp * 4 + 2]), bf16_rn(acc[rb][cb][grp * 4 + 3]));
          *(uint2*)&vt[((size_t)(bb * 8 + hh) * 64 + d) * 2048 + tok] = pk;
        }
      } else {
        float sc = (part == 0) ? 0.125f : 1.0f;
        ushort_t* dsth = (part == 0) ? qh : kho;
        ushort_t* dstl = (part == 0) ? ql : klo;
#pragma unroll
        for (int reg = 0; reg < 16; ++reg) {
          int row = (reg & 3) + 8 * (reg >> 2) + 4 * g;
          int m_g = m_base + row;
          int bb = m_g >> 11, tok = m_g & 2047;
          ushort_t hi, lo;
          split2(acc[rb][cb][reg] * sc, hi, lo);
          size_t addr = ((size_t)(bb * 8 + hh) * 2048 + tok) * 64 + d;
          dsth[addr] = hi;
          dstl[addr] = lo;
        }
      }
    }
  }
}

// ---------------------------------------------------------------------------
// Kernel D: MFMA attention -- R8-proven structure (ds_write staging, stride
// 72 = 0 conflicts, 37 KB = 4 blocks/CU) + VALU micro-cuts:
//   * decay folded with log2e -> pv = exp2f(max(s,0)*dec2)  (1 less mul/elem)
//   * P-store rounding = (u+0x8000)>>16 (2 inst vs 4-5; half-up vs RTNE,
//     differs only at exact ties)
// grid x = bh (XCD affinity), y = qt.
// ---------------------------------------------------------------------------
__global__ __launch_bounds__(256) void attn_mfma(
    const ushort_t* __restrict__ qh, const ushort_t* __restrict__ ql,
    const ushort_t* __restrict__ kho, const ushort_t* __restrict__ klo,
    const ushort_t* __restrict__ vt, const float* __restrict__ R,
    const float* __restrict__ a, const float* __restrict__ c,
    ushort_t* __restrict__ aoh, ushort_t* __restrict__ aol) {
  __shared__ ushort_t KhS[64 * 72], KlS[64 * 72], VtS[64 * 72], PS[64 * 72];
  __shared__ float rsLDS[2][64];

  int tid = threadIdx.x;
  int w = tid >> 6, lane = tid & 63, l31 = lane & 31, g = lane >> 5;
  int qhalf = w >> 1, khalf = w & 1;
  int bh = blockIdx.x;
  int qt = blockIdx.y;
  int b = bh >> 3, h = bh & 7;
  float aab = fabsf(a[h]);
  float cab = fabsf(c[h]);

  size_t qoff = ((size_t)bh * 2048 + qt * 64 + qhalf * 32 + l31) * 64;
  bf16x8 qfh[4], qfl[4];
#pragma unroll
  for (int d0i = 0; d0i < 4; ++d0i) {
    qfh[d0i] = *(const bf16x8*)&qh[qoff + d0i * 16 + 8 * g];
    qfl[d0i] = *(const bf16x8*)&ql[qoff + d0i * 16 + 8 * g];
  }

  int frow[2], fcc[2];
#pragma unroll
  for (int it = 0; it < 2; ++it) {
    int f = tid + it * 256;
    frow[it] = f >> 3;
    fcc[it] = (f & 7) * 8;
  }
  const ushort_t* kbase = kho + (size_t)bh * 2048 * 64;
  const ushort_t* lbase = klo + (size_t)bh * 2048 * 64;
  const ushort_t* vbase = vt + (size_t)bh * 64 * 2048;

  f32x16 oacc;
#pragma unroll
  for (int i = 0; i < 16; ++i) oacc[i] = 0.0f;
  float rs_acc[16] = {};
  int ti = qt >> 1;

#pragma unroll 1
  for (int kt = 0; kt < 32; ++kt) {
    __syncthreads();                      // prev iteration done reading LDS
#pragma unroll
    for (int it = 0; it < 2; ++it) {
      uint4 tk = *(const uint4*)&kbase[(size_t)(kt * 64 + frow[it]) * 64 + fcc[it]];
      uint4 tl = *(const uint4*)&lbase[(size_t)(kt * 64 + frow[it]) * 64 + fcc[it]];
      uint4 tv = *(const uint4*)&vbase[(size_t)frow[it] * 2048 + kt * 64 + fcc[it]];
      int o = frow[it] * 72 + fcc[it];
      *(uint4*)&KhS[o] = tk;
      *(uint4*)&KlS[o] = tl;
      *(uint4*)&VtS[o] = tv;
    }
    __syncthreads();                      // staging visible

    // S = Q K^T (3-product split)
    f32x16 sacc;
#pragma unroll
    for (int i = 0; i < 16; ++i) sacc[i] = 0.0f;
    int krow = (khalf * 32 + l31) * 72;
#pragma unroll
    for (int d0i = 0; d0i < 4; ++d0i) {
      int off = krow + d0i * 16 + 8 * g;
      bf16x8 kfh = *(const bf16x8*)&KhS[off];
      bf16x8 kfl = *(const bf16x8*)&KlS[off];
      sacc = __builtin_amdgcn_mfma_f32_32x32x16_bf16(qfh[d0i], kfh, sacc, 0, 0, 0);
      sacc = __builtin_amdgcn_mfma_f32_32x32x16_bf16(qfh[d0i], kfl, sacc, 0, 0, 0);
      sacc = __builtin_amdgcn_mfma_f32_32x32x16_bf16(qfl[d0i], kfh, sacc, 0, 0, 0);
    }

    float Rv = R[b * (T_ * T_) + ti * T_ + (kt >> 1)];
    float dec2 = 1.44269504f / (1.0f + __expf(aab * Rv - cab));  // decay * log2e
#pragma unroll
    for (int reg = 0; reg < 16; ++reg) {
      float pv = exp2f(fmaxf(sacc[reg], 0.0f) * dec2);
      rs_acc[reg] += pv;
      int row = (reg & 3) + 8 * (reg >> 2) + 4 * g;
      unsigned u = __builtin_bit_cast(unsigned, pv);
      PS[(qhalf * 32 + row) * 72 + khalf * 32 + l31] = (ushort_t)((u + 0x8000u) >> 16);
    }
    __syncthreads();                      // P visible to both k-half waves

#pragma unroll
    for (int k0i = 0; k0i < 4; ++k0i) {
      bf16x8 pf = *(const bf16x8*)&PS[(qhalf * 32 + l31) * 72 + k0i * 16 + 8 * g];
      bf16x8 vf = *(const bf16x8*)&VtS[(khalf * 32 + l31) * 72 + k0i * 16 + 8 * g];
      oacc = __builtin_amdgcn_mfma_f32_32x32x16_bf16(pf, vf, oacc, 0, 0, 0);
    }
  }

  // row-sum combine
#pragma unroll
  for (int reg = 0; reg < 16; ++reg) {
    float vsum = rs_acc[reg];
    vsum += __shfl_xor(vsum, 1);
    vsum += __shfl_xor(vsum, 2);
    vsum += __shfl_xor(vsum, 4);
    vsum += __shfl_xor(vsum, 8);
    vsum += __shfl_xor(vsum, 16);
    rs_acc[reg] = vsum;
  }
  if (l31 == 0) {
#pragma unroll
    for (int reg = 0; reg < 16; ++reg) {
      int row = (reg & 3) + 8 * (reg >> 2) + 4 * g;
      rsLDS[khalf][qhalf * 32 + row] = rs_acc[reg];
    }
  }
  __syncthreads();

  // normalize + write aout hi/lo [b][tok][h*64+d]
#pragma unroll
  for (int reg = 0; reg < 16; ++reg) {
    int row = (reg & 3) + 8 * (reg >> 2) + 4 * g;
    int qg = qhalf * 32 + row;
    float invs = 1.0f / (rsLDS[0][qg] + rsLDS[1][qg]);
    int tok = qt * 64 + qg;
    int d = khalf * 32 + l31;
    ushort_t hi, lo;
    split2(oacc[reg] * invs, hi, lo);
    size_t addr = ((size_t)b * 2048 + tok) * 512 + h * 64 + d;
    aoh[addr] = hi;
    aol[addr] = lo;
  }
}

// ---------------------------------------------------------------------------
// Kernel E: out = aout @ Wout^T. R8-proven body + XCD-aware 1D decode.
// ---------------------------------------------------------------------------
__global__ __launch_bounds__(256) void out_gemm_mfma(
    const ushort_t* __restrict__ ah, const ushort_t* __restrict__ al,
    const ushort_t* __restrict__ wth, const ushort_t* __restrict__ wtl,
    float* __restrict__ out) {
  __shared__ ushort_t Ah[128 * 40], Al[128 * 40], Bh[128 * 40], Bl[128 * 40];
  int tid = threadIdx.x;
  int w = tid >> 6, lane = tid & 63, l31 = lane & 31, g = lane >> 5;
  int wm = w >> 1, wn = w & 1;
  int idx = blockIdx.x;
  int xcd = idx & 7, local = idx >> 3;
  int n0 = (local & 3) * 128;
  int m0 = ((local >> 2) * 8 + xcd) * 128;

  f32x16 acc[2][2];
#pragma unroll
  for (int i = 0; i < 2; ++i)
#pragma unroll
    for (int j = 0; j < 2; ++j)
#pragma unroll
      for (int e = 0; e < 16; ++e) acc[i][j][e] = 0.0f;

  int fm[2], fc[2];
#pragma unroll
  for (int it = 0; it < 2; ++it) {
    int f = tid + it * 256;
    fm[it] = f >> 2;
    fc[it] = (f & 3) * 8;
  }

#pragma unroll 1
  for (int kt = 0; kt < 16; ++kt) {
    __syncthreads();
#pragma unroll
    for (int it = 0; it < 2; ++it) {
      size_t ao = (size_t)(m0 + fm[it]) * 512 + kt * 32 + fc[it];
      size_t bo = (size_t)(n0 + fm[it]) * 512 + kt * 32 + fc[it];
      uint4 tah = *(const uint4*)&ah[ao];
      uint4 tal = *(const uint4*)&al[ao];
      uint4 tbh = *(const uint4*)&wth[bo];
      uint4 tbl = *(const uint4*)&wtl[bo];
      int o = fm[it] * 40 + fc[it];
      *(uint4*)&Ah[o] = tah;
      *(uint4*)&Al[o] = tal;
      *(uint4*)&Bh[o] = tbh;
      *(uint4*)&Bl[o] = tbl;
    }
    __syncthreads();
#pragma unroll
    for (int kc = 0; kc < 2; ++kc) {
      int off = kc * 16 + 8 * g;
      bf16x8 afh[2], afl[2], bfh[2], bfl[2];
#pragma unroll
      for (int rb = 0; rb < 2; ++rb) {
        int r = (wm * 64 + rb * 32 + l31) * 40 + off;
        afh[rb] = *(const bf16x8*)&Ah[r];
        afl[rb] = *(const bf16x8*)&Al[r];
      }
#pragma unroll
      for (int cb = 0; cb < 2; ++cb) {
        int r = (wn * 64 + cb * 32 + l31) * 40 + off;
        bfh[cb] = *(const bf16x8*)&Bh[r];
        bfl[cb] = *(const bf16x8*)&Bl[r];
      }
#pragma unroll
      for (int rb = 0; rb < 2; ++rb)
#pragma unroll
        for (int cb = 0; cb < 2; ++cb) {
          acc[rb][cb] = __builtin_amdgcn_mfma_f32_32x32x16_bf16(afh[rb], bfh[cb], acc[rb][cb], 0, 0, 0);
          acc[rb][cb] = __builtin_amdgcn_mfma_f32_32x32x16_bf16(afh[rb], bfl[cb], acc[rb][cb], 0, 0, 0);
          acc[rb][cb] = __builtin_amdgcn_mfma_f32_32x32x16_bf16(afl[rb], bfh[cb], acc[rb][cb], 0, 0, 0);
        }
    }
  }

#pragma unroll
  for (int rb = 0; rb < 2; ++rb) {
    int m_base = m0 + wm * 64 + rb * 32;
#pragma unroll
    for (int cb = 0; cb < 2; ++cb) {
      int n_g = n0 + wn * 64 + cb * 32 + l31;
#pragma unroll
      for (int reg = 0; reg < 16; ++reg) {
        int row = (reg & 3) + 8 * (reg >> 2) + 4 * g;
        out[(size_t)(m_base + row) * 512 + n_g] = acc[rb][cb][reg];
      }
    }
  }
}

// ---------------------------------------------------------------------------
extern "C" void kernel_launch(void* const* d_in, const int* in_sizes, int n_in,
                              void* d_out, int out_size, void* d_ws, size_t ws_size,
                              hipStream_t stream) {
  (void)in_sizes; (void)n_in;
  const float* x     = (const float*)d_in[0];
  const float* R     = (const float*)d_in[1];
  const float* gamma = (const float*)d_in[2];
  const float* beta  = (const float*)d_in[3];
  const float* Wqkv  = (const float*)d_in[4];
  const float* Wout  = (const float*)d_in[5];
  const float* av    = (const float*)d_in[6];
  const float* cv    = (const float*)d_in[7];
  float* out = (float*)d_out;

  const size_t EL  = (size_t)B_ * N_ * DIM_;     // 4,194,304 elements
  const size_t SZT = EL * sizeof(ushort_t);      // 8 MiB per bf16 tensor

  char* p = (char*)d_ws;
  ushort_t* wqh = (ushort_t*)p;                  p += (size_t)1536 * 512 * 2;
  ushort_t* wql = (ushort_t*)p;                  p += (size_t)1536 * 512 * 2;
  ushort_t* woh = (ushort_t*)p;                  p += (size_t)512 * 512 * 2;
  ushort_t* wol = (ushort_t*)p;                  p += (size_t)512 * 512 * 2;
  ushort_t* qhb = (ushort_t*)p;                  p += SZT;
  ushort_t* qlb = (ushort_t*)p;                  p += SZT;
  ushort_t* khb = (ushort_t*)p;                  p += SZT;
  ushort_t* klb = (ushort_t*)p;                  p += SZT;
  ushort_t* vtb = (ushort_t*)p;                  p += SZT;
  size_t base_need = (size_t)(p - (char*)d_ws);
  size_t needA = base_need + 2 * SZT;

  bool planA = (ws_size >= needA);
  // xn hi/lo doubles as aout hi/lo (xn dead after qkv_gemm).
  ushort_t* xnh = planA ? (ushort_t*)p : (ushort_t*)d_out;
  ushort_t* xnl = xnh + EL;
  float* gemm_dst = planA ? out : (float*)qhb;   // qh+ql region dead by then

  prep_kernel<<<dim3(2304), dim3(256), 0, stream>>>(x, gamma, beta, Wqkv, Wout,
                                                    xnh, xnl, wqh, wql, woh, wol);
  qkv_gemm_mfma<<<dim3(768), dim3(256), 0, stream>>>(xnh, xnl, wqh, wql,
                                                     qhb, qlb, khb, klb, vtb);
  attn_mfma<<<dim3(32, 32), dim3(256), 0, stream>>>(qhb, qlb, khb, klb, vtb,
                                                    R, av, cv, xnh, xnl);
  out_gemm_mfma<<<dim3(256), dim3(256), 0, stream>>>(xnh, xnl, woh, wol, gemm_dst);
  if (!planA) {
    hipMemcpyAsync(out, gemm_dst, (size_t)out_size * sizeof(float),
                   hipMemcpyDeviceToDevice, stream);
  }
}

// Round 11
// 245.768 us; speedup vs baseline: 1.0983x; 1.0896x over previous
//
#include <hip/hip_runtime.h>
#include <math.h>

#define B_   4
#define N_   2048
#define DIM_ 512
#define T_   16
#define H_   8
#define DH_  64
// num_patches = 128; 64-token tiles align within patches -> decay scalar per tile pair

typedef unsigned short ushort_t;
typedef __attribute__((ext_vector_type(8))) short bf16x8;    // 8 bf16 = 4 VGPRs
typedef __attribute__((ext_vector_type(16))) float f32x16;   // 32x32 MFMA acc

__device__ inline ushort_t bf16_rn(float x) {
  unsigned u = __builtin_bit_cast(unsigned, x);
  u += 0x7FFFu + ((u >> 16) & 1u);
  return (ushort_t)(u >> 16);
}
__device__ inline float bf16f(ushort_t h) {
  return __builtin_bit_cast(float, (unsigned)h << 16);
}
__device__ inline unsigned pack2(ushort_t a, ushort_t b) {
  return (unsigned)a | ((unsigned)b << 16);
}
__device__ inline void split2(float x, ushort_t &h, ushort_t &l) {
  h = bf16_rn(x);
  l = bf16_rn(x - bf16f(h));
}

// ---------------------------------------------------------------------------
// Kernel A: merged prep. Blocks 0..191: Wqkv transpose+split; 192..255: Wout;
// 256..2303: LayerNorm -> xn hi/lo.
// ---------------------------------------------------------------------------
__global__ __launch_bounds__(256) void prep_kernel(
    const float* __restrict__ x, const float* __restrict__ gamma,
    const float* __restrict__ beta, const float* __restrict__ Wqkv,
    const float* __restrict__ Wout,
    ushort_t* __restrict__ xnh, ushort_t* __restrict__ xnl,
    ushort_t* __restrict__ wqh, ushort_t* __restrict__ wql,
    ushort_t* __restrict__ woh, ushort_t* __restrict__ wol) {
  __shared__ float Ts[64][68];
  int bidx = blockIdx.x;
  int tid = threadIdx.x;
  if (bidx < 256) {
    const float* src; ushort_t* dh; ushort_t* dl; int Nn, n0, k0;
    if (bidx < 192) {
      src = Wqkv; dh = wqh; dl = wql; Nn = 1536;
      n0 = (bidx % 24) * 64; k0 = (bidx / 24) * 64;
    } else {
      int l = bidx - 192;
      src = Wout; dh = woh; dl = wol; Nn = 512;
      n0 = (l % 8) * 64; k0 = (l / 8) * 64;
    }
#pragma unroll
    for (int it = 0; it < 4; ++it) {
      int idx = tid + it * 256;
      int r = idx >> 4, c4 = (idx & 15) * 4;
      *(float4*)&Ts[r][c4] = *(const float4*)&src[(size_t)(k0 + r) * Nn + n0 + c4];
    }
    __syncthreads();
#pragma unroll
    for (int it = 0; it < 2; ++it) {
      int idx = tid + it * 256;
      int n = idx >> 3, kc = (idx & 7) * 8;
      ushort_t hs[8], ls[8];
#pragma unroll
      for (int j = 0; j < 8; ++j) split2(Ts[kc + j][n], hs[j], ls[j]);
      uint4 uh, ul;
      uh.x = pack2(hs[0], hs[1]); uh.y = pack2(hs[2], hs[3]);
      uh.z = pack2(hs[4], hs[5]); uh.w = pack2(hs[6], hs[7]);
      ul.x = pack2(ls[0], ls[1]); ul.y = pack2(ls[2], ls[3]);
      ul.z = pack2(ls[4], ls[5]); ul.w = pack2(ls[6], ls[7]);
      size_t o = (size_t)(n0 + n) * 512 + k0 + kc;
      *(uint4*)&dh[o] = uh;
      *(uint4*)&dl[o] = ul;
    }
  } else {
    int row  = (bidx - 256) * 4 + (tid >> 6);
    int lane = tid & 63;
    const float4* xr = (const float4*)(x + (size_t)row * DIM_);
    float4 v0 = xr[lane * 2 + 0];
    float4 v1 = xr[lane * 2 + 1];
    float s  = v0.x + v0.y + v0.z + v0.w + v1.x + v1.y + v1.z + v1.w;
    float ss = v0.x*v0.x + v0.y*v0.y + v0.z*v0.z + v0.w*v0.w
             + v1.x*v1.x + v1.y*v1.y + v1.z*v1.z + v1.w*v1.w;
#pragma unroll
    for (int off = 32; off > 0; off >>= 1) {
      s  += __shfl_xor(s, off);
      ss += __shfl_xor(ss, off);
    }
    float mu  = s * (1.0f / DIM_);
    float var = ss * (1.0f / DIM_) - mu * mu;
    float rstd = rsqrtf(var + 1e-5f);
    float4 g0 = *(const float4*)&gamma[lane * 8];
    float4 g1 = *(const float4*)&gamma[lane * 8 + 4];
    float4 b0 = *(const float4*)&beta[lane * 8];
    float4 b1 = *(const float4*)&beta[lane * 8 + 4];
    float xv[8] = {v0.x, v0.y, v0.z, v0.w, v1.x, v1.y, v1.z, v1.w};
    float gv[8] = {g0.x, g0.y, g0.z, g0.w, g1.x, g1.y, g1.z, g1.w};
    float bv[8] = {b0.x, b0.y, b0.z, b0.w, b1.x, b1.y, b1.z, b1.w};
    ushort_t hs[8], ls[8];
#pragma unroll
    for (int j = 0; j < 8; ++j) {
      float xn = (xv[j] - mu) * rstd * gv[j] + bv[j];
      split2(xn, hs[j], ls[j]);
    }
    uint4 uh, ul;
    uh.x = pack2(hs[0], hs[1]); uh.y = pack2(hs[2], hs[3]);
    uh.z = pack2(hs[4], hs[5]); uh.w = pack2(hs[6], hs[7]);
    ul.x = pack2(ls[0], ls[1]); ul.y = pack2(ls[2], ls[3]);
    ul.z = pack2(ls[4], ls[5]); ul.w = pack2(ls[6], ls[7]);
    size_t o = (size_t)row * DIM_ + lane * 8;
    *(uint4*)&xnh[o] = uh;
    *(uint4*)&xnl[o] = ul;
  }
}

// ---------------------------------------------------------------------------
// Kernel C: qkv = xn @ Wqkv^T (R8-proven body + XCD-aware 1D decode). Kept
// identical to R10 (rest-of-pipeline improved 150->141 us with this).
// ---------------------------------------------------------------------------
__global__ __launch_bounds__(256) void qkv_gemm_mfma(
    const ushort_t* __restrict__ xnh, const ushort_t* __restrict__ xnl,
    const ushort_t* __restrict__ wth, const ushort_t* __restrict__ wtl,
    ushort_t* __restrict__ qh, ushort_t* __restrict__ ql,
    ushort_t* __restrict__ kho, ushort_t* __restrict__ klo,
    ushort_t* __restrict__ vt) {
  __shared__ ushort_t Ah[128 * 40], Al[128 * 40], Bh[128 * 40], Bl[128 * 40];
  int tid = threadIdx.x;
  int w = tid >> 6, lane = tid & 63, l31 = lane & 31, g = lane >> 5;
  int wm = w >> 1, wn = w & 1;
  int idx = blockIdx.x;
  int xcd = idx & 7, local = idx >> 3;
  int n0 = (local % 12) * 128;
  int m0 = ((local / 12) * 8 + xcd) * 128;

  f32x16 acc[2][2];
#pragma unroll
  for (int i = 0; i < 2; ++i)
#pragma unroll
    for (int j = 0; j < 2; ++j)
#pragma unroll
      for (int e = 0; e < 16; ++e) acc[i][j][e] = 0.0f;

  int fm[2], fc[2];
#pragma unroll
  for (int it = 0; it < 2; ++it) {
    int f = tid + it * 256;
    fm[it] = f >> 2;
    fc[it] = (f & 3) * 8;
  }

#pragma unroll 1
  for (int kt = 0; kt < 16; ++kt) {
    __syncthreads();
#pragma unroll
    for (int it = 0; it < 2; ++it) {
      size_t ao = (size_t)(m0 + fm[it]) * 512 + kt * 32 + fc[it];
      size_t bo = (size_t)(n0 + fm[it]) * 512 + kt * 32 + fc[it];
      uint4 tah = *(const uint4*)&xnh[ao];
      uint4 tal = *(const uint4*)&xnl[ao];
      uint4 tbh = *(const uint4*)&wth[bo];
      uint4 tbl = *(const uint4*)&wtl[bo];
      int o = fm[it] * 40 + fc[it];
      *(uint4*)&Ah[o] = tah;
      *(uint4*)&Al[o] = tal;
      *(uint4*)&Bh[o] = tbh;
      *(uint4*)&Bl[o] = tbl;
    }
    __syncthreads();
#pragma unroll
    for (int kc = 0; kc < 2; ++kc) {
      int off = kc * 16 + 8 * g;
      bf16x8 afh[2], afl[2], bfh[2], bfl[2];
#pragma unroll
      for (int rb = 0; rb < 2; ++rb) {
        int r = (wm * 64 + rb * 32 + l31) * 40 + off;
        afh[rb] = *(const bf16x8*)&Ah[r];
        afl[rb] = *(const bf16x8*)&Al[r];
      }
#pragma unroll
      for (int cb = 0; cb < 2; ++cb) {
        int r = (wn * 64 + cb * 32 + l31) * 40 + off;
        bfh[cb] = *(const bf16x8*)&Bh[r];
        bfl[cb] = *(const bf16x8*)&Bl[r];
      }
#pragma unroll
      for (int rb = 0; rb < 2; ++rb)
#pragma unroll
        for (int cb = 0; cb < 2; ++cb) {
          acc[rb][cb] = __builtin_amdgcn_mfma_f32_32x32x16_bf16(afh[rb], bfh[cb], acc[rb][cb], 0, 0, 0);
          acc[rb][cb] = __builtin_amdgcn_mfma_f32_32x32x16_bf16(afh[rb], bfl[cb], acc[rb][cb], 0, 0, 0);
          acc[rb][cb] = __builtin_amdgcn_mfma_f32_32x32x16_bf16(afl[rb], bfh[cb], acc[rb][cb], 0, 0, 0);
        }
    }
  }

  int part = n0 >> 9;
#pragma unroll
  for (int rb = 0; rb < 2; ++rb) {
    int m_base = m0 + wm * 64 + rb * 32;
#pragma unroll
    for (int cb = 0; cb < 2; ++cb) {
      int n_g = n0 + wn * 64 + cb * 32 + l31;
      int rem = n_g & 511, hh = rem >> 6, d = rem & 63;
      if (part == 2) {
#pragma unroll
        for (int grp = 0; grp < 4; ++grp) {
          int m_g = m_base + grp * 8 + 4 * g;
          int bb = m_g >> 11, tok = m_g & 2047;
          uint2 pk;
          pk.x = pack2(bf16_rn(acc[rb][cb][grp * 4 + 0]), bf16_rn(acc[rb][cb][grp * 4 + 1]));
          pk.y = pack2(bf16_rn(acc[rb][cb][grp * 4 + 2]), bf16_rn(acc[rb][cb][grp * 4 + 3]));
          *(uint2*)&vt[((size_t)(bb * 8 + hh) * 64 + d) * 2048 + tok] = pk;
        }
      } else {
        float sc = (part == 0) ? 0.125f : 1.0f;
        ushort_t* dsth = (part == 0) ? qh : kho;
        ushort_t* dstl = (part == 0) ? ql : klo;
#pragma unroll
        for (int reg = 0; reg < 16; ++reg) {
          int row = (reg & 3) + 8 * (reg >> 2) + 4 * g;
          int m_g = m_base + row;
          int bb = m_g >> 11, tok = m_g & 2047;
          ushort_t hi, lo;
          split2(acc[rb][cb][reg] * sc, hi, lo);
          size_t addr = ((size_t)(bb * 8 + hh) * 2048 + tok) * 64 + d;
          dsth[addr] = hi;
          dstl[addr] = lo;
        }
      }
    }
  }
}

// ---------------------------------------------------------------------------
// Kernel D: MFMA attention, 256 queries/block, 512 threads (8 waves).
// Each wave owns 32 q-rows x ALL 64 keys: P is wave-local (no P barrier,
// no rsLDS), K/V staged once per 256 q (4x less staging), 2 barriers/kt.
// R8-exact numerics (__expf, bf16_rn). LDS 64512 B. grid (bh=32, qt=8):
// linear id % 8 == bh % 8 -> XCD affinity.
// ---------------------------------------------------------------------------
__global__ __launch_bounds__(512) void attn_mfma(
    const ushort_t* __restrict__ qh, const ushort_t* __restrict__ ql,
    const ushort_t* __restrict__ kho, const ushort_t* __restrict__ klo,
    const ushort_t* __restrict__ vt, const float* __restrict__ R,
    const float* __restrict__ a, const float* __restrict__ c,
    ushort_t* __restrict__ aoh, ushort_t* __restrict__ aol) {
  __shared__ ushort_t KhS[64 * 72], KlS[64 * 72], VtS[64 * 72];
  __shared__ ushort_t PS[256 * 72];

  int tid = threadIdx.x;
  int w = tid >> 6, lane = tid & 63, l31 = lane & 31, g = lane >> 5;
  int bh = blockIdx.x;
  int qt = blockIdx.y;               // 256-query tile
  int b = bh >> 3, h = bh & 7;
  float aab = fabsf(a[h]);
  float cab = fabsf(c[h]);

  // Q fragments: wave w owns rows qt*256 + w*32 .. +32
  int qrow = qt * 256 + w * 32 + l31;
  size_t qoff = ((size_t)bh * 2048 + qrow) * 64;
  bf16x8 qfh[4], qfl[4];
#pragma unroll
  for (int d0i = 0; d0i < 4; ++d0i) {
    qfh[d0i] = *(const bf16x8*)&qh[qoff + d0i * 16 + 8 * g];
    qfl[d0i] = *(const bf16x8*)&ql[qoff + d0i * 16 + 8 * g];
  }

  int frow = tid >> 3;               // 0..63
  int fcc = (tid & 7) * 8;
  const ushort_t* kbase = kho + (size_t)bh * 2048 * 64;
  const ushort_t* lbase = klo + (size_t)bh * 2048 * 64;
  const ushort_t* vbase = vt + (size_t)bh * 64 * 2048;

  f32x16 oacc[2];
#pragma unroll
  for (int t = 0; t < 2; ++t)
#pragma unroll
    for (int i = 0; i < 16; ++i) oacc[t][i] = 0.0f;
  float rs_acc[16] = {};
  int ti = qt * 2 + (w >> 2);        // 128 tokens per timepoint patch

#pragma unroll 1
  for (int kt = 0; kt < 32; ++kt) {
    __syncthreads();                 // prev iteration done reading K/V LDS
    {
      uint4 tk = *(const uint4*)&kbase[(size_t)(kt * 64 + frow) * 64 + fcc];
      uint4 tl = *(const uint4*)&lbase[(size_t)(kt * 64 + frow) * 64 + fcc];
      uint4 tv = *(const uint4*)&vbase[(size_t)frow * 2048 + kt * 64 + fcc];
      int o = frow * 72 + fcc;
      *(uint4*)&KhS[o] = tk;
      *(uint4*)&KlS[o] = tl;
      *(uint4*)&VtS[o] = tv;
    }
    __syncthreads();                 // staging visible

    float Rv = R[b * (T_ * T_) + ti * T_ + (kt >> 1)];
    float dec = 1.0f / (1.0f + __expf(aab * Rv - cab));

    // S = Q K^T for both key halves; P write is wave-local
#pragma unroll
    for (int khalf = 0; khalf < 2; ++khalf) {
      f32x16 sacc;
#pragma unroll
      for (int i = 0; i < 16; ++i) sacc[i] = 0.0f;
      int krow = (khalf * 32 + l31) * 72;
#pragma unroll
      for (int d0i = 0; d0i < 4; ++d0i) {
        int off = krow + d0i * 16 + 8 * g;
        bf16x8 kfh = *(const bf16x8*)&KhS[off];
        bf16x8 kfl = *(const bf16x8*)&KlS[off];
        sacc = __builtin_amdgcn_mfma_f32_32x32x16_bf16(qfh[d0i], kfh, sacc, 0, 0, 0);
        sacc = __builtin_amdgcn_mfma_f32_32x32x16_bf16(qfh[d0i], kfl, sacc, 0, 0, 0);
        sacc = __builtin_amdgcn_mfma_f32_32x32x16_bf16(qfl[d0i], kfh, sacc, 0, 0, 0);
      }
#pragma unroll
      for (int reg = 0; reg < 16; ++reg) {
        float pv = __expf(fmaxf(sacc[reg], 0.0f) * dec);
        rs_acc[reg] += pv;
        int row = (reg & 3) + 8 * (reg >> 2) + 4 * g;
        PS[(w * 32 + row) * 72 + khalf * 32 + l31] = bf16_rn(pv);
      }
    }

    // O += P V  (P rows are this wave's own -- no barrier needed)
    bf16x8 pf[4];
#pragma unroll
    for (int k0i = 0; k0i < 4; ++k0i)
      pf[k0i] = *(const bf16x8*)&PS[(w * 32 + l31) * 72 + k0i * 16 + 8 * g];
#pragma unroll
    for (int dt = 0; dt < 2; ++dt) {
      int vrow = (dt * 32 + l31) * 72;
#pragma unroll
      for (int k0i = 0; k0i < 4; ++k0i) {
        bf16x8 vf = *(const bf16x8*)&VtS[vrow + k0i * 16 + 8 * g];
        oacc[dt] = __builtin_amdgcn_mfma_f32_32x32x16_bf16(pf[k0i], vf, oacc[dt], 0, 0, 0);
      }
    }
  }

  // row sums: fully in-wave (cols = l31 lanes; both g halves hold distinct rows)
#pragma unroll
  for (int reg = 0; reg < 16; ++reg) {
    float vsum = rs_acc[reg];
    vsum += __shfl_xor(vsum, 1);
    vsum += __shfl_xor(vsum, 2);
    vsum += __shfl_xor(vsum, 4);
    vsum += __shfl_xor(vsum, 8);
    vsum += __shfl_xor(vsum, 16);
    rs_acc[reg] = vsum;
  }

  // normalize + write aout hi/lo [b][tok][h*64+d]
#pragma unroll
  for (int reg = 0; reg < 16; ++reg) {
    int row = (reg & 3) + 8 * (reg >> 2) + 4 * g;
    float invs = 1.0f / rs_acc[reg];
    int tok = qt * 256 + w * 32 + row;
#pragma unroll
    for (int dt = 0; dt < 2; ++dt) {
      int d = dt * 32 + l31;
      ushort_t hi, lo;
      split2(oacc[dt][reg] * invs, hi, lo);
      size_t addr = ((size_t)b * 2048 + tok) * 512 + h * 64 + d;
      aoh[addr] = hi;
      aol[addr] = lo;
    }
  }
}

// ---------------------------------------------------------------------------
// Kernel E: out = aout @ Wout^T. R8-proven body + XCD-aware 1D decode.
// ---------------------------------------------------------------------------
__global__ __launch_bounds__(256) void out_gemm_mfma(
    const ushort_t* __restrict__ ah, const ushort_t* __restrict__ al,
    const ushort_t* __restrict__ wth, const ushort_t* __restrict__ wtl,
    float* __restrict__ out) {
  __shared__ ushort_t Ah[128 * 40], Al[128 * 40], Bh[128 * 40], Bl[128 * 40];
  int tid = threadIdx.x;
  int w = tid >> 6, lane = tid & 63, l31 = lane & 31, g = lane >> 5;
  int wm = w >> 1, wn = w & 1;
  int idx = blockIdx.x;
  int xcd = idx & 7, local = idx >> 3;
  int n0 = (local & 3) * 128;
  int m0 = ((local >> 2) * 8 + xcd) * 128;

  f32x16 acc[2][2];
#pragma unroll
  for (int i = 0; i < 2; ++i)
#pragma unroll
    for (int j = 0; j < 2; ++j)
#pragma unroll
      for (int e = 0; e < 16; ++e) acc[i][j][e] = 0.0f;

  int fm[2], fc[2];
#pragma unroll
  for (int it = 0; it < 2; ++it) {
    int f = tid + it * 256;
    fm[it] = f >> 2;
    fc[it] = (f & 3) * 8;
  }

#pragma unroll 1
  for (int kt = 0; kt < 16; ++kt) {
    __syncthreads();
#pragma unroll
    for (int it = 0; it < 2; ++it) {
      size_t ao = (size_t)(m0 + fm[it]) * 512 + kt * 32 + fc[it];
      size_t bo = (size_t)(n0 + fm[it]) * 512 + kt * 32 + fc[it];
      uint4 tah = *(const uint4*)&ah[ao];
      uint4 tal = *(const uint4*)&al[ao];
      uint4 tbh = *(const uint4*)&wth[bo];
      uint4 tbl = *(const uint4*)&wtl[bo];
      int o = fm[it] * 40 + fc[it];
      *(uint4*)&Ah[o] = tah;
      *(uint4*)&Al[o] = tal;
      *(uint4*)&Bh[o] = tbh;
      *(uint4*)&Bl[o] = tbl;
    }
    __syncthreads();
#pragma unroll
    for (int kc = 0; kc < 2; ++kc) {
      int off = kc * 16 + 8 * g;
      bf16x8 afh[2], afl[2], bfh[2], bfl[2];
#pragma unroll
      for (int rb = 0; rb < 2; ++rb) {
        int r = (wm * 64 + rb * 32 + l31) * 40 + off;
        afh[rb] = *(const bf16x8*)&Ah[r];
        afl[rb] = *(const bf16x8*)&Al[r];
      }
#pragma unroll
      for (int cb = 0; cb < 2; ++cb) {
        int r = (wn * 64 + cb * 32 + l31) * 40 + off;
        bfh[cb] = *(const bf16x8*)&Bh[r];
        bfl[cb] = *(const bf16x8*)&Bl[r];
      }
#pragma unroll
      for (int rb = 0; rb < 2; ++rb)
#pragma unroll
        for (int cb = 0; cb < 2; ++cb) {
          acc[rb][cb] = __builtin_amdgcn_mfma_f32_32x32x16_bf16(afh[rb], bfh[cb], acc[rb][cb], 0, 0, 0);
          acc[rb][cb] = __builtin_amdgcn_mfma_f32_32x32x16_bf16(afh[rb], bfl[cb], acc[rb][cb], 0, 0, 0);
          acc[rb][cb] = __builtin_amdgcn_mfma_f32_32x32x16_bf16(afl[rb], bfh[cb], acc[rb][cb], 0, 0, 0);
        }
    }
  }

#pragma unroll
  for (int rb = 0; rb < 2; ++rb) {
    int m_base = m0 + wm * 64 + rb * 32;
#pragma unroll
    for (int cb = 0; cb < 2; ++cb) {
      int n_g = n0 + wn * 64 + cb * 32 + l31;
#pragma unroll
      for (int reg = 0; reg < 16; ++reg) {
        int row = (reg & 3) + 8 * (reg >> 2) + 4 * g;
        out[(size_t)(m_base + row) * 512 + n_g] = acc[rb][cb][reg];
      }
    }
  }
}

// ---------------------------------------------------------------------------
extern "C" void kernel_launch(void* const* d_in, const int* in_sizes, int n_in,
                              void* d_out, int out_size, void* d_ws, size_t ws_size,
                              hipStream_t stream) {
  (void)in_sizes; (void)n_in;
  const float* x     = (const float*)d_in[0];
  const float* R     = (const float*)d_in[1];
  const float* gamma = (const float*)d_in[2];
  const float* beta  = (const float*)d_in[3];
  const float* Wqkv  = (const float*)d_in[4];
  const float* Wout  = (const float*)d_in[5];
  const float* av    = (const float*)d_in[6];
  const float* cv    = (const float*)d_in[7];
  float* out = (float*)d_out;

  const size_t EL  = (size_t)B_ * N_ * DIM_;     // 4,194,304 elements
  const size_t SZT = EL * sizeof(ushort_t);      // 8 MiB per bf16 tensor

  char* p = (char*)d_ws;
  ushort_t* wqh = (ushort_t*)p;                  p += (size_t)1536 * 512 * 2;
  ushort_t* wql = (ushort_t*)p;                  p += (size_t)1536 * 512 * 2;
  ushort_t* woh = (ushort_t*)p;                  p += (size_t)512 * 512 * 2;
  ushort_t* wol = (ushort_t*)p;                  p += (size_t)512 * 512 * 2;
  ushort_t* qhb = (ushort_t*)p;                  p += SZT;
  ushort_t* qlb = (ushort_t*)p;                  p += SZT;
  ushort_t* khb = (ushort_t*)p;                  p += SZT;
  ushort_t* klb = (ushort_t*)p;                  p += SZT;
  ushort_t* vtb = (ushort_t*)p;                  p += SZT;
  size_t base_need = (size_t)(p - (char*)d_ws);
  size_t needA = base_need + 2 * SZT;

  bool planA = (ws_size >= needA);
  ushort_t* xnh = planA ? (ushort_t*)p : (ushort_t*)d_out;
  ushort_t* xnl = xnh + EL;
  float* gemm_dst = planA ? out : (float*)qhb;

  prep_kernel<<<dim3(2304), dim3(256), 0, stream>>>(x, gamma, beta, Wqkv, Wout,
                                                    xnh, xnl, wqh, wql, woh, wol);
  qkv_gemm_mfma<<<dim3(768), dim3(256), 0, stream>>>(xnh, xnl, wqh, wql,
                                                     qhb, qlb, khb, klb, vtb);
  attn_mfma<<<dim3(32, 8), dim3(512), 0, stream>>>(qhb, qlb, khb, klb, vtb,
                                                   R, av, cv, xnh, xnl);
  out_gemm_mfma<<<dim3(256), dim3(256), 0, stream>>>(xnh, xnl, woh, wol, gemm_dst);
  if (!planA) {
    hipMemcpyAsync(out, gemm_dst, (size_t)out_size * sizeof(float),
                   hipMemcpyDeviceToDevice, stream);
  }
}